// Round 14
// baseline (229.600 us; speedup 1.0000x reference)
//
#include <hip/hip_runtime.h>

#define DEV_INLINE __device__ __forceinline__

constexpr int BATCH = 2;
constexpr int HH = 96, WW = 96, CC = 96;
constexpr int DI = 192;
constexpr int NS = 16;
constexpr int LSEQ = HH * WW;        // 9216
constexpr int TT = BATCH * LSEQ;     // 18432
constexpr int CHUNK = 16;
constexpr int NCHUNK = LSEQ / CHUNK; // 576 per batch
constexpr int SUP = 24, NSUP = NCHUNK / SUP; // 24
constexpr int QDN = DI * NS;         // 3072

typedef __attribute__((ext_vector_type(8))) short bf16x8;
typedef __attribute__((ext_vector_type(4))) float f32x4;

DEV_INLINE float silu_f(float x) { return x / (1.f + __expf(-x)); }
DEV_INLINE float softplus_f(float x) {
  return fmaxf(x, 0.f) + log1pf(__expf(-fabsf(x)));
}
DEV_INLINE ushort f2bf(float f) {
  union { float f; unsigned u; } c; c.f = f;
  unsigned u = c.u + 0x7FFF + ((c.u >> 16) & 1);   // RNE
  return (ushort)(u >> 16);
}
DEV_INLINE float bf2f(ushort u) {
  union { unsigned u; float f; } c; c.u = ((unsigned)u) << 16; return c.f;
}

// ---------------- weight cast/transpose, coalesced READS ----------------
__global__ __launch_bounds__(256)
void castw_kernel(const float* __restrict__ w0, const float* __restrict__ w1,
                  const float* __restrict__ w2, const float* __restrict__ w3,
                  const float* __restrict__ wx, const float* __restrict__ wdt,
                  const float* __restrict__ wc1,
                  ushort* __restrict__ t0, ushort* __restrict__ t1,
                  ushort* __restrict__ t2, ushort* __restrict__ t3,
                  ushort* __restrict__ t4, ushort* __restrict__ t5,
                  float* __restrict__ cwT)
{
  int id = blockIdx.x * 256 + threadIdx.x;      // 187968 total
  if (id < 36864) {                              // in_proj W[96][384] -> [384][96]
    int k = id / 384, n = id % 384;
    t0[n * 96 + k] = f2bf(w0[id]);
  } else if (id < 110592) {                      // m_in W[192][384] -> [384][192]
    int j = id - 36864; int k = j / 384, n = j % 384;
    t1[n * 192 + k] = f2bf(w1[j]);
  } else if (id < 147456) {                      // m_out W[192][192] -> [192][192]
    int j = id - 110592; int k = j / 192, n = j % 192;
    t2[n * 192 + k] = f2bf(w2[j]);
  } else if (id < 165888) {                      // out W[192][96] -> [128][192]
    int j = id - 147456; int k = j / 96, n = j % 96;
    t3[n * 192 + k] = f2bf(w3[j]);
  } else if (id < 172032) {                      // zero rows 96..127
    int j = id - 165888;
    t3[96 * 192 + j] = 0;
  } else if (id < 180480) {                      // x_proj W[192][44] -> Wxt[48][192] permuted
    int j = id - 172032; int k = j / 44, c = j % 44;
    int r = (c < 12) ? (32 + c) : (c < 28 ? (c - 12) : (16 + c - 28));
    t4[r * 192 + k] = f2bf(wx[j]);
  } else if (id < 181248) {                      // zero rows 44..47
    int j = id - 180480;
    t4[44 * 192 + j] = 0;
  } else if (id < 183552) {                      // dt_proj W[12][192] -> Wdtt[192][32]
    int j = id - 181248; int r = j / 192, d = j % 192;
    t5[d * 32 + r] = f2bf(wdt[j]);
  } else if (id < 187392) {                      // zero cols 12..31
    int j = id - 183552; int d = j / 20, r = 12 + j % 20;
    t5[d * 32 + r] = 0;
  } else if (id < 187968) {                      // conv1d w[192][3] -> cwT[3][192]
    int j = id - 187392; int d = j / 3, k = j % 3;
    cwT[k * 192 + d] = wc1[j];
  }
}

// ---------------- fused LayerNorm + in_proj MFMA GEMM ----------------
__global__ __launch_bounds__(256)
void ln_inproj_kernel(const float* __restrict__ x, const float* __restrict__ nw,
                      const float* __restrict__ nbias, const ushort* __restrict__ Wt0,
                      ushort* __restrict__ xz0)
{
  __shared__ ushort sA[128][104];
  const int tid = threadIdx.x;
  const int m0 = blockIdx.x * 128;
  const int n0 = blockIdx.y * 64;
  {
    const int tok = tid >> 1, h = tid & 1;
    const float* xr = x + (size_t)(m0 + tok) * 96 + h * 48;
    float v[48];
    float s = 0.f, ss = 0.f;
#pragma unroll
    for (int i = 0; i < 12; ++i) {
      float4 t4 = *(const float4*)(xr + i * 4);
      v[i*4+0] = t4.x; v[i*4+1] = t4.y; v[i*4+2] = t4.z; v[i*4+3] = t4.w;
      s += (t4.x + t4.y) + (t4.z + t4.w);
      ss += (t4.x*t4.x + t4.y*t4.y) + (t4.z*t4.z + t4.w*t4.w);
    }
    s += __shfl_xor(s, 1);
    ss += __shfl_xor(ss, 1);
    float mean = s * (1.f/96.f);
    float var = ss * (1.f/96.f) - mean*mean;
    float rstd = rsqrtf(var + 1e-5f);
    const float* wr = nw + h*48;
    const float* br = nbias + h*48;
#pragma unroll
    for (int i = 0; i < 12; ++i) {
      float4 w4 = *(const float4*)(wr + i*4);
      float4 b4 = *(const float4*)(br + i*4);
      unsigned p0 = (unsigned)f2bf((v[i*4+0]-mean)*rstd*w4.x + b4.x)
                  | ((unsigned)f2bf((v[i*4+1]-mean)*rstd*w4.y + b4.y) << 16);
      unsigned p1 = (unsigned)f2bf((v[i*4+2]-mean)*rstd*w4.z + b4.z)
                  | ((unsigned)f2bf((v[i*4+3]-mean)*rstd*w4.w + b4.w) << 16);
      unsigned* dst = (unsigned*)&sA[tok][h*48 + i*4];
      dst[0] = p0; dst[1] = p1;
    }
  }
  __syncthreads();

  const int wid = tid >> 6, lane = tid & 63;
  const int wm = wid >> 1, wn = wid & 1;
  const int l16 = lane & 15, quad = lane >> 4;
  const f32x4 z4 = {0.f, 0.f, 0.f, 0.f};
  f32x4 acc[4][2];
#pragma unroll
  for (int i = 0; i < 4; ++i)
#pragma unroll
    for (int j = 0; j < 2; ++j) acc[i][j] = z4;

#pragma unroll
  for (int k0 = 0; k0 < 96; k0 += 32) {
    bf16x8 xf[4], wf[2];
#pragma unroll
    for (int i = 0; i < 4; ++i)
      xf[i] = *(const bf16x8*)&sA[wm*64 + i*16 + l16][k0 + quad*8];
#pragma unroll
    for (int j = 0; j < 2; ++j)
      wf[j] = *(const bf16x8*)(Wt0 + (size_t)(n0 + wn*32 + j*16 + l16) * 96 + k0 + quad*8);
#pragma unroll
    for (int i = 0; i < 4; ++i)
#pragma unroll
      for (int j = 0; j < 2; ++j)
        acc[i][j] = __builtin_amdgcn_mfma_f32_16x16x32_bf16(wf[j], xf[i], acc[i][j], 0, 0, 0);
  }
#pragma unroll
  for (int i = 0; i < 4; ++i) {
    const int token = m0 + wm*64 + i*16 + l16;
#pragma unroll
    for (int j = 0; j < 2; ++j) {
      const int nb = n0 + wn*32 + j*16 + quad*4;
      ushort4 o;
      o.x = f2bf(acc[i][j][0]); o.y = f2bf(acc[i][j][1]);
      o.z = f2bf(acc[i][j][2]); o.w = f2bf(acc[i][j][3]);
      *(ushort4*)(xz0 + (size_t)token * 384 + nb) = o;
    }
  }
}

// ---------------- depthwise 3x3 conv + SiLU, bf16 in/out ----------------
__global__ __launch_bounds__(256)
void conv2d_silu_kernel(const ushort* __restrict__ xz0, const float* __restrict__ w,
                        ushort* __restrict__ xc)
{
  __shared__ float ws[DI * 9];
  for (int i = threadIdx.x; i < DI * 9; i += 256) ws[i] = w[i];
  __syncthreads();
  int id = blockIdx.x * 256 + threadIdx.x;     // TT*48
  int dq = id % 48;
  int p  = id / 48;
  int j = p % WW;
  int i = (p / WW) % HH;
  int b = p / (WW * HH);
  int d = dq * 4;
  float a0 = 0.f, a1 = 0.f, a2 = 0.f, a3 = 0.f;
#pragma unroll
  for (int ki = 0; ki < 3; ++ki) {
    int ii = i + ki - 1;
    if (ii < 0 || ii >= HH) continue;
#pragma unroll
    for (int kj = 0; kj < 3; ++kj) {
      int jj = j + kj - 1;
      if (jj < 0 || jj >= WW) continue;
      const ushort4 v = *(const ushort4*)(xz0 + ((size_t)((b * HH + ii) * WW + jj)) * 384 + d);
      int wk = ki * 3 + kj;
      a0 = fmaf(bf2f(v.x), ws[(d + 0) * 9 + wk], a0);
      a1 = fmaf(bf2f(v.y), ws[(d + 1) * 9 + wk], a1);
      a2 = fmaf(bf2f(v.z), ws[(d + 2) * 9 + wk], a2);
      a3 = fmaf(bf2f(v.w), ws[(d + 3) * 9 + wk], a3);
    }
  }
  ushort4 o;
  o.x = f2bf(silu_f(a0)); o.y = f2bf(silu_f(a1));
  o.z = f2bf(silu_f(a2)); o.w = f2bf(silu_f(a3));
  *(ushort4*)(xc + (size_t)p * DI + d) = o;
}

// ---------------- bf16 MFMA GEMM (m_in_proj) ----------------
__global__ __launch_bounds__(256)
void mfma_gemm_kernel(const ushort* __restrict__ A, int lda,
                      const ushort* __restrict__ Bt, int ldb,
                      ushort* __restrict__ Cout, int ldc, int K)
{
  const int tid = threadIdx.x;
  const int wid = tid >> 6, lane = tid & 63;
  const int wm = wid >> 1, wn = wid & 1;
  const int m0 = blockIdx.x * 128 + wm * 64;
  const int n0 = blockIdx.y * 64 + wn * 32;
  const int l16 = lane & 15, quad = lane >> 4;

  f32x4 acc[4][2];
  const f32x4 z4 = {0.f, 0.f, 0.f, 0.f};
#pragma unroll
  for (int i = 0; i < 4; ++i)
#pragma unroll
    for (int j = 0; j < 2; ++j) acc[i][j] = z4;

  for (int k0 = 0; k0 < K; k0 += 32) {
    bf16x8 xf[4], wf[2];
#pragma unroll
    for (int i = 0; i < 4; ++i)
      xf[i] = *(const bf16x8*)(A + (size_t)(m0 + i * 16 + l16) * lda + k0 + quad * 8);
#pragma unroll
    for (int j = 0; j < 2; ++j)
      wf[j] = *(const bf16x8*)(Bt + (size_t)(n0 + j * 16 + l16) * ldb + k0 + quad * 8);
#pragma unroll
    for (int i = 0; i < 4; ++i)
#pragma unroll
      for (int j = 0; j < 2; ++j)
        acc[i][j] = __builtin_amdgcn_mfma_f32_16x16x32_bf16(wf[j], xf[i], acc[i][j], 0, 0, 0);
  }
#pragma unroll
  for (int i = 0; i < 4; ++i) {
    const int token = m0 + i * 16 + l16;
#pragma unroll
    for (int j = 0; j < 2; ++j) {
      const int nb = n0 + j * 16 + quad * 4;
      ushort4 o;
      o.x = f2bf(acc[i][j][0]); o.y = f2bf(acc[i][j][1]);
      o.z = f2bf(acc[i][j][2]); o.w = f2bf(acc[i][j][3]);
      *(ushort4*)(Cout + (size_t)token * ldc + nb) = o;
    }
  }
}

// ---------------- fused mamba prep + chunk-local scan (LDS-prefetched conv) ------------
__global__ __launch_bounds__(256)
void mprep_kernel(const ushort* __restrict__ xz1, const float* __restrict__ cwT,
                  const float* __restrict__ cb, const ushort* __restrict__ Wxt,
                  const ushort* __restrict__ Wdtt, const float* __restrict__ bdt,
                  const float* __restrict__ Alog,
                  ushort* __restrict__ xmb, ushort* __restrict__ dlt,
                  float* __restrict__ bc, unsigned* __restrict__ PE)
{
  __shared__ ushort sxm[32][204];
  __shared__ union {
    ushort sxz[34][200];    // phase a: staged xz1 rows [T0-2, T0+32), cols 0..191
    ushort sdlt[32][204];   // phase b/c: delta
  } u;
  __shared__ float sbc[32][36];
  const int tid = threadIdx.x;
  const int bid = blockIdx.x;
  const int T0 = bid * 32;
  const f32x4 z4 = {0.f, 0.f, 0.f, 0.f};

  // phase a0: bulk coalesced prefetch of xz1 tile -> LDS (816 independent uint4 loads)
  for (int i = tid; i < 34 * 24; i += 256) {
    int r = i / 24, c = i % 24;
    int t = T0 - 2 + r;
    uint4 v = make_uint4(0u, 0u, 0u, 0u);
    if (t >= 0) v = *(const uint4*)(xz1 + (size_t)t * 384 + c * 8);
    *(uint4*)&u.sxz[r][c * 8] = v;
  }
  __syncthreads();

  // phase a1: causal conv1d + bias + SiLU from LDS
  for (int task = tid; task < 1536; task += 256) {
    int dq = task % 48, tok = task / 48;
    int t = T0 + tok, l = t % LSEQ;
    int d = dq * 4;
    float4 b4 = *(const float4*)(cb + d);
    float a0 = b4.x, a1 = b4.y, a2 = b4.z, a3 = b4.w;
#pragma unroll
    for (int k = 0; k < 3; ++k) {
      if (l + k - 2 < 0) continue;
      const ushort4 v = *(const ushort4*)&u.sxz[tok + k][d];
      const float4 w4 = *(const float4*)(cwT + k * 192 + d);
      a0 = fmaf(bf2f(v.x), w4.x, a0);
      a1 = fmaf(bf2f(v.y), w4.y, a1);
      a2 = fmaf(bf2f(v.z), w4.z, a2);
      a3 = fmaf(bf2f(v.w), w4.w, a3);
    }
    ushort4 o;
    o.x = f2bf(silu_f(a0)); o.y = f2bf(silu_f(a1));
    o.z = f2bf(silu_f(a2)); o.w = f2bf(silu_f(a3));
    *(ushort4*)&sxm[tok][d] = o;
    *(ushort4*)(xmb + (size_t)t * DI + d) = o;
  }
  __syncthreads();

  // phase b: x_proj (B,C | dt->dt_proj) by wave role
  {
    const int wv = tid >> 6, lane = tid & 63;
    const int l16 = lane & 15, quad = lane >> 4;
    const int s = wv & 1, role = wv >> 1;
    const int tokb = s * 16;
    if (role == 0) {
      f32x4 aB = z4, aC = z4;
#pragma unroll
      for (int k0 = 0; k0 < 192; k0 += 32) {
        bf16x8 uf = *(const bf16x8*)&sxm[tokb + l16][k0 + quad * 8];
        bf16x8 wB = *(const bf16x8*)(Wxt + (size_t)(l16) * 192 + k0 + quad * 8);
        bf16x8 wC = *(const bf16x8*)(Wxt + (size_t)(16 + l16) * 192 + k0 + quad * 8);
        aB = __builtin_amdgcn_mfma_f32_16x16x32_bf16(wB, uf, aB, 0, 0, 0);
        aC = __builtin_amdgcn_mfma_f32_16x16x32_bf16(wC, uf, aC, 0, 0, 0);
      }
      float4 vB = make_float4(aB[0], aB[1], aB[2], aB[3]);
      float4 vC = make_float4(aC[0], aC[1], aC[2], aC[3]);
      *(float4*)&sbc[tokb + l16][quad * 4] = vB;
      *(float4*)&sbc[tokb + l16][16 + quad * 4] = vC;
      *(float4*)(bc + (size_t)(T0 + tokb + l16) * 32 + quad * 4) = vB;
      *(float4*)(bc + (size_t)(T0 + tokb + l16) * 32 + 16 + quad * 4) = vC;
    } else {
      f32x4 aD = z4;
#pragma unroll
      for (int k0 = 0; k0 < 192; k0 += 32) {
        bf16x8 uf = *(const bf16x8*)&sxm[tokb + l16][k0 + quad * 8];
        bf16x8 wD = *(const bf16x8*)(Wxt + (size_t)(32 + l16) * 192 + k0 + quad * 8);
        aD = __builtin_amdgcn_mfma_f32_16x16x32_bf16(wD, uf, aD, 0, 0, 0);
      }
      bf16x8 dtf;
#pragma unroll
      for (int j = 0; j < 8; ++j) {
        int n = quad * 8 + j;
        int src = ((n >> 2) & 3) * 16 + l16;
        float tv = __shfl(aD[j & 3], src);
        dtf[j] = (short)((n < 16) ? f2bf(tv) : (ushort)0);
      }
      f32x4 a2[12];
#pragma unroll
      for (int jj = 0; jj < 12; ++jj) {
        bf16x8 wf = *(const bf16x8*)(Wdtt + (size_t)(jj * 16 + l16) * 32 + quad * 8);
        a2[jj] = __builtin_amdgcn_mfma_f32_16x16x32_bf16(wf, dtf, z4, 0, 0, 0);
      }
#pragma unroll
      for (int jj = 0; jj < 12; ++jj) {
        const int nb = jj * 16 + quad * 4;
        const float4 b4 = *(const float4*)(bdt + nb);
        ushort4 o;
        o.x = f2bf(softplus_f(a2[jj][0] + b4.x));
        o.y = f2bf(softplus_f(a2[jj][1] + b4.y));
        o.z = f2bf(softplus_f(a2[jj][2] + b4.z));
        o.w = f2bf(softplus_f(a2[jj][3] + b4.w));
        *(ushort4*)&u.sdlt[tokb + l16][nb] = o;
        *(ushort4*)(dlt + (size_t)(T0 + tokb + l16) * DI + nb) = o;
      }
    }
  }
  __syncthreads();

  // phase c: chunk-local scan -> packed P|E
  for (int task = tid; task < 384; task += 256) {
    const int d = task % 192, c = task / 192;
    float Av[16];
#pragma unroll
    for (int j = 0; j < 16; ++j) Av[j] = -__expf(Alog[d * 16 + j]);
    float e[16];
#pragma unroll
    for (int j = 0; j < 16; ++j) e[j] = 0.f;
    float sdl = 0.f;
    for (int l = 0; l < CHUNK; ++l) {
      const int tl = c * 16 + l;
      float dl = bf2f(u.sdlt[tl][d]);
      float uu = bf2f(sxm[tl][d]);
      const float4 B0 = *(const float4*)&sbc[tl][0];
      const float4 B1 = *(const float4*)&sbc[tl][4];
      const float4 B2 = *(const float4*)&sbc[tl][8];
      const float4 B3 = *(const float4*)&sbc[tl][12];
      const float Bv[16] = {B0.x, B0.y, B0.z, B0.w, B1.x, B1.y, B1.z, B1.w,
                            B2.x, B2.y, B2.z, B2.w, B3.x, B3.y, B3.z, B3.w};
      float du = dl * uu;
      sdl += dl;
#pragma unroll
      for (int j = 0; j < 16; ++j) {
        float a = __expf(dl * Av[j]);
        e[j] = fmaf(a, e[j], du * Bv[j]);
      }
    }
    const int batch = bid / 288;
    const int gci = (bid % 288) * 2 + c;
    size_t base = ((size_t)(batch * NCHUNK + gci)) * QDN + d;
#pragma unroll
    for (int j = 0; j < 16; ++j) {
      unsigned p = f2bf(__expf(Av[j] * sdl));
      unsigned ev = f2bf(e[j]);
      PE[base + j * 192] = (p << 16) | ev;
    }
  }
}

// ---------------- scan2a: per-super product/accum (packed P|E in) ----------------
__global__ __launch_bounds__(256)
void scan2a_kernel(const unsigned* __restrict__ PE,
                   float* __restrict__ SP, float* __restrict__ SE)
{
  int id = blockIdx.x * 256 + threadIdx.x;  // BATCH*NSUP*QDN = 147456
  int q = id % QDN;
  int s = (id / QDN) % NSUP;
  int b = id / (QDN * NSUP);
  float cp = 1.f, ce = 0.f;
#pragma unroll 6
  for (int c = 0; c < SUP; ++c) {
    unsigned pe = PE[((size_t)(b * NCHUNK + s * SUP + c)) * QDN + q];
    float p = bf2f((ushort)(pe >> 16));
    float e = bf2f((ushort)(pe & 0xFFFF));
    ce = fmaf(p, ce, e);
    cp *= p;
  }
  SP[id] = cp; SE[id] = ce;
}

// ---------------- scan2b: serial over NSUP supers ----------------
__global__ __launch_bounds__(256)
void scan2b_kernel(const float* __restrict__ SP, const float* __restrict__ SE,
                   float* __restrict__ Hsup)
{
  int id = blockIdx.x * 256 + threadIdx.x;  // BATCH*QDN = 6144
  int q = id % QDN;
  int b = id / QDN;
  float carry = 0.f;
#pragma unroll
  for (int s = 0; s < NSUP; ++s) {
    size_t idx = ((size_t)(b * NSUP + s)) * QDN + q;
    Hsup[idx] = carry;
    carry = fmaf(SP[idx], carry, SE[idx]);
  }
}

// ---------------- scan2c: expand to per-chunk inbound (bf16 out) ----------------
__global__ __launch_bounds__(256)
void scan2c_kernel(const unsigned* __restrict__ PE, const float* __restrict__ Hsup,
                   ushort* __restrict__ Hin)
{
  int id = blockIdx.x * 256 + threadIdx.x;  // 147456
  int q = id % QDN;
  int s = (id / QDN) % NSUP;
  int b = id / (QDN * NSUP);
  float h = Hsup[id];
#pragma unroll 6
  for (int c = 0; c < SUP; ++c) {
    size_t idx = ((size_t)(b * NCHUNK + s * SUP + c)) * QDN + q;
    Hin[idx] = f2bf(h);
    unsigned pe = PE[idx];
    float p = bf2f((ushort)(pe >> 16));
    float e = bf2f((ushort)(pe & 0xFFFF));
    h = fmaf(p, h, e);
  }
}

// ---------------- fused scan3 replay + m_out_proj (gate) + out_proj (+residual) --------
__global__ __launch_bounds__(256)
void scan3_outproj_kernel(const ushort* __restrict__ dlt, const ushort* __restrict__ xmb,
                          const float* __restrict__ bc, const float* __restrict__ Alog,
                          const float* __restrict__ Dv, const ushort* __restrict__ xz1,
                          const ushort* __restrict__ Hin, const ushort* __restrict__ xz0,
                          const ushort* __restrict__ Wt2, const ushort* __restrict__ Wt3,
                          const float* __restrict__ x, float* __restrict__ out)
{
  __shared__ float sBC[CHUNK][32];
  __shared__ ushort sY[16][204];
  __shared__ ushort sYG[16][204];
  const int tid = threadIdx.x;
  const int g = blockIdx.x % NCHUNK;
  const int b = blockIdx.x / NCHUNK;
  const int t0 = b * LSEQ + g * CHUNK;
  const f32x4 z4 = {0.f, 0.f, 0.f, 0.f};

  for (int i = tid; i < CHUNK * 32; i += 256) {
    int l = i >> 5, j = i & 31;
    sBC[l][j] = bc[(size_t)(t0 + l) * 32 + j];
  }
  if (tid < 192) {
    const int d = tid;
    float Av[16];
#pragma unroll
    for (int j = 0; j < 16; ++j) Av[j] = -__expf(Alog[d * 16 + j]);
    const float Dd = Dv[d];
    float h[16];
    {
      size_t hb = ((size_t)(b * NCHUNK + g)) * QDN + d;
#pragma unroll
      for (int j = 0; j < 16; ++j) h[j] = bf2f(Hin[hb + j * 192]);
    }
    __syncthreads();
#pragma unroll 4
    for (int l = 0; l < CHUNK; ++l) {
      const int t = t0 + l;
      float dl = bf2f(dlt[(size_t)t * DI + d]);
      float u  = bf2f(xmb[(size_t)t * DI + d]);
      float z  = bf2f(xz1[(size_t)t * 384 + 192 + d]);
      float du = dl * u;
      float y0 = 0.f, y1 = 0.f, y2 = 0.f, y3 = 0.f;
#pragma unroll
      for (int j = 0; j < 16; ++j) {
        float a = __expf(dl * Av[j]);
        h[j] = fmaf(a, h[j], du * sBC[l][j]);
        float hc = h[j] * sBC[l][16 + j];
        if ((j & 3) == 0) y0 += hc;
        else if ((j & 3) == 1) y1 += hc;
        else if ((j & 3) == 2) y2 += hc;
        else y3 += hc;
      }
      float y = (y0 + y1) + (y2 + y3) + u * Dd;
      sY[l][d] = f2bf(y * silu_f(z));
    }
  } else {
    __syncthreads();
  }
  __syncthreads();

  const int wv = tid >> 6, lane = tid & 63;
  const int l16 = lane & 15, quad = lane >> 4;
  const int token = t0 + l16;

  // GEMM1: yg[16][192] = y @ Wt2^T + silu gate
  {
    f32x4 acc1[3] = {z4, z4, z4};
#pragma unroll
    for (int k0 = 0; k0 < 192; k0 += 32) {
      bf16x8 af = *(const bf16x8*)&sY[l16][k0 + quad * 8];
#pragma unroll
      for (int i = 0; i < 3; ++i) {
        const int tt = wv + i * 4;
        bf16x8 wf = *(const bf16x8*)(Wt2 + (size_t)(tt * 16 + l16) * 192 + k0 + quad * 8);
        acc1[i] = __builtin_amdgcn_mfma_f32_16x16x32_bf16(wf, af, acc1[i], 0, 0, 0);
      }
    }
#pragma unroll
    for (int i = 0; i < 3; ++i) {
      const int nb = (wv + i * 4) * 16 + quad * 4;
      const ushort4 g4 = *(const ushort4*)(xz0 + (size_t)token * 384 + 192 + nb);
      unsigned p0 = (unsigned)f2bf(acc1[i][0] * silu_f(bf2f(g4.x)))
                  | ((unsigned)f2bf(acc1[i][1] * silu_f(bf2f(g4.y))) << 16);
      unsigned p1 = (unsigned)f2bf(acc1[i][2] * silu_f(bf2f(g4.z)))
                  | ((unsigned)f2bf(acc1[i][3] * silu_f(bf2f(g4.w))) << 16);
      unsigned* dst = (unsigned*)&sYG[l16][nb];
      dst[0] = p0; dst[1] = p1;
    }
  }
  __syncthreads();

  // GEMM2: out[16][96] = yg @ Wt3^T + x
#pragma unroll
  for (int rep = 0; rep < 2; ++rep) {
    const int tt = wv + rep * 4;
    if (tt >= 6) break;
    f32x4 acc2 = z4;
#pragma unroll
    for (int k0 = 0; k0 < 192; k0 += 32) {
      bf16x8 af = *(const bf16x8*)&sYG[l16][k0 + quad * 8];
      bf16x8 wf = *(const bf16x8*)(Wt3 + (size_t)(tt * 16 + l16) * 192 + k0 + quad * 8);
      acc2 = __builtin_amdgcn_mfma_f32_16x16x32_bf16(wf, af, acc2, 0, 0, 0);
    }
    const int nb = tt * 16 + quad * 4;
    const float4 r4 = *(const float4*)(x + (size_t)token * 96 + nb);
    *(float4*)(out + (size_t)token * 96 + nb) =
        make_float4(acc2[0] + r4.x, acc2[1] + r4.y, acc2[2] + r4.z, acc2[3] + r4.w);
  }
}

// ---------------- launch ----------------
extern "C" void kernel_launch(void* const* d_in, const int* in_sizes, int n_in,
                              void* d_out, int out_size, void* d_ws, size_t ws_size,
                              hipStream_t stream)
{
  const float* x         = (const float*)d_in[0];
  const float* norm_w    = (const float*)d_in[1];
  const float* norm_b    = (const float*)d_in[2];
  const float* in_proj_w = (const float*)d_in[3];
  const float* conv2d_w  = (const float*)d_in[4];
  const float* m_in_proj = (const float*)d_in[5];
  const float* m_c1d_w   = (const float*)d_in[6];
  const float* m_c1d_b   = (const float*)d_in[7];
  const float* m_x_proj  = (const float*)d_in[8];
  const float* m_dt_w    = (const float*)d_in[9];
  const float* m_dt_b    = (const float*)d_in[10];
  const float* m_A_log   = (const float*)d_in[11];
  const float* m_D       = (const float*)d_in[12];
  const float* m_out_w   = (const float*)d_in[13];
  const float* out_w     = (const float*)d_in[14];
  float* out = (float*)d_out;

  char* wp = (char*)d_ws;
  auto alloc = [&](size_t bytes) {
    char* r = wp; wp += (bytes + 255) & ~(size_t)255; return r;
  };
  ushort* Wt0    = (ushort*)alloc(36864 * 2);      // [384][96]
  ushort* Wt1    = (ushort*)alloc(73728 * 2);      // [384][192]
  ushort* Wt2    = (ushort*)alloc(36864 * 2);      // [192][192]
  ushort* Wt3    = (ushort*)alloc(24576 * 2);      // [128][192]
  ushort* Wxt    = (ushort*)alloc(9216 * 2);       // [48][192]
  ushort* Wdtt   = (ushort*)alloc(6144 * 2);       // [192][32]
  float*  cw1T   = (float*)alloc(576 * 4);         // [3][192]
  ushort* xz0    = (ushort*)alloc((size_t)TT * 384 * 2);
  ushort* xc_bf  = (ushort*)alloc((size_t)TT * 192 * 2);
  ushort* xz1    = (ushort*)alloc((size_t)TT * 384 * 2);
  ushort* xmb_bf = (ushort*)alloc((size_t)TT * 192 * 2);
  float*  bc     = (float*)alloc((size_t)TT * 32 * 4);
  ushort* dlt    = (ushort*)alloc((size_t)TT * 192 * 2);
  unsigned* PE   = (unsigned*)alloc((size_t)BATCH * NCHUNK * QDN * 4);
  float*  SP     = (float*)alloc((size_t)BATCH * NSUP * QDN * 4);
  float*  SE     = (float*)alloc((size_t)BATCH * NSUP * QDN * 4);
  float*  Hsup   = (float*)alloc((size_t)BATCH * NSUP * QDN * 4);
  ushort* Hin    = (ushort*)alloc((size_t)BATCH * NCHUNK * QDN * 2);

  castw_kernel<<<735, 256, 0, stream>>>(in_proj_w, m_in_proj, m_out_w, out_w,
                                        m_x_proj, m_dt_w, m_c1d_w,
                                        Wt0, Wt1, Wt2, Wt3, Wxt, Wdtt, cw1T);
  ln_inproj_kernel<<<dim3(TT / 128, 6), 256, 0, stream>>>(x, norm_w, norm_b, Wt0, xz0);
  conv2d_silu_kernel<<<TT * 48 / 256, 256, 0, stream>>>(xz0, conv2d_w, xc_bf);
  mfma_gemm_kernel<<<dim3(TT / 128, 6), 256, 0, stream>>>(xc_bf, 192, Wt1, 192, xz1, 384, 192);
  mprep_kernel<<<TT / 32, 256, 0, stream>>>(xz1, cw1T, m_c1d_b, Wxt, Wdtt, m_dt_b,
                                            m_A_log, xmb_bf, dlt, bc, PE);
  scan2a_kernel<<<BATCH * NSUP * QDN / 256, 256, 0, stream>>>(PE, SP, SE);
  scan2b_kernel<<<BATCH * QDN / 256, 256, 0, stream>>>(SP, SE, Hsup);
  scan2c_kernel<<<BATCH * NSUP * QDN / 256, 256, 0, stream>>>(PE, Hsup, Hin);
  scan3_outproj_kernel<<<BATCH * NCHUNK, 256, 0, stream>>>(
      dlt, xmb_bf, bc, m_A_log, m_D, xz1, Hin, xz0, Wt2, Wt3, x, out);
}

// Round 15
// 226.512 us; speedup vs baseline: 1.0136x; 1.0136x over previous
//
#include <hip/hip_runtime.h>

#define DEV_INLINE __device__ __forceinline__

constexpr int BATCH = 2;
constexpr int HH = 96, WW = 96, CC = 96;
constexpr int DI = 192;
constexpr int NS = 16;
constexpr int LSEQ = HH * WW;        // 9216
constexpr int TT = BATCH * LSEQ;     // 18432
constexpr int CHUNK = 16;
constexpr int NCHUNK = LSEQ / CHUNK; // 576 per batch
constexpr int SUP = 24, NSUP = NCHUNK / SUP; // 24
constexpr int QDN = DI * NS;         // 3072

typedef __attribute__((ext_vector_type(8))) short bf16x8;
typedef __attribute__((ext_vector_type(4))) float f32x4;

DEV_INLINE float silu_f(float x) { return x / (1.f + __expf(-x)); }
DEV_INLINE float softplus_f(float x) {
  return fmaxf(x, 0.f) + log1pf(__expf(-fabsf(x)));
}
DEV_INLINE ushort f2bf(float f) {
  union { float f; unsigned u; } c; c.f = f;
  unsigned u = c.u + 0x7FFF + ((c.u >> 16) & 1);   // RNE
  return (ushort)(u >> 16);
}
DEV_INLINE float bf2f(ushort u) {
  union { unsigned u; float f; } c; c.u = ((unsigned)u) << 16; return c.f;
}

// ---------------- weight cast/transpose, coalesced READS ----------------
__global__ __launch_bounds__(256)
void castw_kernel(const float* __restrict__ w0, const float* __restrict__ w1,
                  const float* __restrict__ w2, const float* __restrict__ w3,
                  const float* __restrict__ wx, const float* __restrict__ wdt,
                  const float* __restrict__ wc1,
                  ushort* __restrict__ t0, ushort* __restrict__ t1,
                  ushort* __restrict__ t2, ushort* __restrict__ t3,
                  ushort* __restrict__ t4, ushort* __restrict__ t5,
                  float* __restrict__ cwT)
{
  int id = blockIdx.x * 256 + threadIdx.x;      // 187968 total
  if (id < 36864) {                              // in_proj W[96][384] -> [384][96]
    int k = id / 384, n = id % 384;
    t0[n * 96 + k] = f2bf(w0[id]);
  } else if (id < 110592) {                      // m_in W[192][384] -> [384][192]
    int j = id - 36864; int k = j / 384, n = j % 384;
    t1[n * 192 + k] = f2bf(w1[j]);
  } else if (id < 147456) {                      // m_out W[192][192] -> [192][192]
    int j = id - 110592; int k = j / 192, n = j % 192;
    t2[n * 192 + k] = f2bf(w2[j]);
  } else if (id < 165888) {                      // out W[192][96] -> [128][192]
    int j = id - 147456; int k = j / 96, n = j % 96;
    t3[n * 192 + k] = f2bf(w3[j]);
  } else if (id < 172032) {                      // zero rows 96..127
    int j = id - 165888;
    t3[96 * 192 + j] = 0;
  } else if (id < 180480) {                      // x_proj W[192][44] -> Wxt[48][192] permuted
    int j = id - 172032; int k = j / 44, c = j % 44;
    int r = (c < 12) ? (32 + c) : (c < 28 ? (c - 12) : (16 + c - 28));
    t4[r * 192 + k] = f2bf(wx[j]);
  } else if (id < 181248) {                      // zero rows 44..47
    int j = id - 180480;
    t4[44 * 192 + j] = 0;
  } else if (id < 183552) {                      // dt_proj W[12][192] -> Wdtt[192][32]
    int j = id - 181248; int r = j / 192, d = j % 192;
    t5[d * 32 + r] = f2bf(wdt[j]);
  } else if (id < 187392) {                      // zero cols 12..31
    int j = id - 183552; int d = j / 20, r = 12 + j % 20;
    t5[d * 32 + r] = 0;
  } else if (id < 187968) {                      // conv1d w[192][3] -> cwT[3][192]
    int j = id - 187392; int d = j / 3, k = j % 3;
    cwT[k * 192 + d] = wc1[j];
  }
}

// ---------------- fused LayerNorm + in_proj MFMA GEMM ----------------
__global__ __launch_bounds__(256)
void ln_inproj_kernel(const float* __restrict__ x, const float* __restrict__ nw,
                      const float* __restrict__ nbias, const ushort* __restrict__ Wt0,
                      ushort* __restrict__ xz0)
{
  __shared__ ushort sA[128][104];
  const int tid = threadIdx.x;
  const int m0 = blockIdx.x * 128;
  const int n0 = blockIdx.y * 64;
  {
    const int tok = tid >> 1, h = tid & 1;
    const float* xr = x + (size_t)(m0 + tok) * 96 + h * 48;
    float v[48];
    float s = 0.f, ss = 0.f;
#pragma unroll
    for (int i = 0; i < 12; ++i) {
      float4 t4 = *(const float4*)(xr + i * 4);
      v[i*4+0] = t4.x; v[i*4+1] = t4.y; v[i*4+2] = t4.z; v[i*4+3] = t4.w;
      s += (t4.x + t4.y) + (t4.z + t4.w);
      ss += (t4.x*t4.x + t4.y*t4.y) + (t4.z*t4.z + t4.w*t4.w);
    }
    s += __shfl_xor(s, 1);
    ss += __shfl_xor(ss, 1);
    float mean = s * (1.f/96.f);
    float var = ss * (1.f/96.f) - mean*mean;
    float rstd = rsqrtf(var + 1e-5f);
    const float* wr = nw + h*48;
    const float* br = nbias + h*48;
#pragma unroll
    for (int i = 0; i < 12; ++i) {
      float4 w4 = *(const float4*)(wr + i*4);
      float4 b4 = *(const float4*)(br + i*4);
      unsigned p0 = (unsigned)f2bf((v[i*4+0]-mean)*rstd*w4.x + b4.x)
                  | ((unsigned)f2bf((v[i*4+1]-mean)*rstd*w4.y + b4.y) << 16);
      unsigned p1 = (unsigned)f2bf((v[i*4+2]-mean)*rstd*w4.z + b4.z)
                  | ((unsigned)f2bf((v[i*4+3]-mean)*rstd*w4.w + b4.w) << 16);
      unsigned* dst = (unsigned*)&sA[tok][h*48 + i*4];
      dst[0] = p0; dst[1] = p1;
    }
  }
  __syncthreads();

  const int wid = tid >> 6, lane = tid & 63;
  const int wm = wid >> 1, wn = wid & 1;
  const int l16 = lane & 15, quad = lane >> 4;
  const f32x4 z4 = {0.f, 0.f, 0.f, 0.f};
  f32x4 acc[4][2];
#pragma unroll
  for (int i = 0; i < 4; ++i)
#pragma unroll
    for (int j = 0; j < 2; ++j) acc[i][j] = z4;

#pragma unroll
  for (int k0 = 0; k0 < 96; k0 += 32) {
    bf16x8 xf[4], wf[2];
#pragma unroll
    for (int i = 0; i < 4; ++i)
      xf[i] = *(const bf16x8*)&sA[wm*64 + i*16 + l16][k0 + quad*8];
#pragma unroll
    for (int j = 0; j < 2; ++j)
      wf[j] = *(const bf16x8*)(Wt0 + (size_t)(n0 + wn*32 + j*16 + l16) * 96 + k0 + quad*8);
#pragma unroll
    for (int i = 0; i < 4; ++i)
#pragma unroll
      for (int j = 0; j < 2; ++j)
        acc[i][j] = __builtin_amdgcn_mfma_f32_16x16x32_bf16(wf[j], xf[i], acc[i][j], 0, 0, 0);
  }
#pragma unroll
  for (int i = 0; i < 4; ++i) {
    const int token = m0 + wm*64 + i*16 + l16;
#pragma unroll
    for (int j = 0; j < 2; ++j) {
      const int nb = n0 + wn*32 + j*16 + quad*4;
      ushort4 o;
      o.x = f2bf(acc[i][j][0]); o.y = f2bf(acc[i][j][1]);
      o.z = f2bf(acc[i][j][2]); o.w = f2bf(acc[i][j][3]);
      *(ushort4*)(xz0 + (size_t)token * 384 + nb) = o;
    }
  }
}

// ---------------- depthwise 3x3 conv + SiLU, bf16 in/out ----------------
__global__ __launch_bounds__(256)
void conv2d_silu_kernel(const ushort* __restrict__ xz0, const float* __restrict__ w,
                        ushort* __restrict__ xc)
{
  __shared__ float ws[DI * 9];
  for (int i = threadIdx.x; i < DI * 9; i += 256) ws[i] = w[i];
  __syncthreads();
  int id = blockIdx.x * 256 + threadIdx.x;     // TT*48
  int dq = id % 48;
  int p  = id / 48;
  int j = p % WW;
  int i = (p / WW) % HH;
  int b = p / (WW * HH);
  int d = dq * 4;
  float a0 = 0.f, a1 = 0.f, a2 = 0.f, a3 = 0.f;
#pragma unroll
  for (int ki = 0; ki < 3; ++ki) {
    int ii = i + ki - 1;
    if (ii < 0 || ii >= HH) continue;
#pragma unroll
    for (int kj = 0; kj < 3; ++kj) {
      int jj = j + kj - 1;
      if (jj < 0 || jj >= WW) continue;
      const ushort4 v = *(const ushort4*)(xz0 + ((size_t)((b * HH + ii) * WW + jj)) * 384 + d);
      int wk = ki * 3 + kj;
      a0 = fmaf(bf2f(v.x), ws[(d + 0) * 9 + wk], a0);
      a1 = fmaf(bf2f(v.y), ws[(d + 1) * 9 + wk], a1);
      a2 = fmaf(bf2f(v.z), ws[(d + 2) * 9 + wk], a2);
      a3 = fmaf(bf2f(v.w), ws[(d + 3) * 9 + wk], a3);
    }
  }
  ushort4 o;
  o.x = f2bf(silu_f(a0)); o.y = f2bf(silu_f(a1));
  o.z = f2bf(silu_f(a2)); o.w = f2bf(silu_f(a3));
  *(ushort4*)(xc + (size_t)p * DI + d) = o;
}

// ---------------- bf16 MFMA GEMM (m_in_proj) ----------------
__global__ __launch_bounds__(256)
void mfma_gemm_kernel(const ushort* __restrict__ A, int lda,
                      const ushort* __restrict__ Bt, int ldb,
                      ushort* __restrict__ Cout, int ldc, int K)
{
  const int tid = threadIdx.x;
  const int wid = tid >> 6, lane = tid & 63;
  const int wm = wid >> 1, wn = wid & 1;
  const int m0 = blockIdx.x * 128 + wm * 64;
  const int n0 = blockIdx.y * 64 + wn * 32;
  const int l16 = lane & 15, quad = lane >> 4;

  f32x4 acc[4][2];
  const f32x4 z4 = {0.f, 0.f, 0.f, 0.f};
#pragma unroll
  for (int i = 0; i < 4; ++i)
#pragma unroll
    for (int j = 0; j < 2; ++j) acc[i][j] = z4;

  for (int k0 = 0; k0 < K; k0 += 32) {
    bf16x8 xf[4], wf[2];
#pragma unroll
    for (int i = 0; i < 4; ++i)
      xf[i] = *(const bf16x8*)(A + (size_t)(m0 + i * 16 + l16) * lda + k0 + quad * 8);
#pragma unroll
    for (int j = 0; j < 2; ++j)
      wf[j] = *(const bf16x8*)(Bt + (size_t)(n0 + j * 16 + l16) * ldb + k0 + quad * 8);
#pragma unroll
    for (int i = 0; i < 4; ++i)
#pragma unroll
      for (int j = 0; j < 2; ++j)
        acc[i][j] = __builtin_amdgcn_mfma_f32_16x16x32_bf16(wf[j], xf[i], acc[i][j], 0, 0, 0);
  }
#pragma unroll
  for (int i = 0; i < 4; ++i) {
    const int token = m0 + i * 16 + l16;
#pragma unroll
    for (int j = 0; j < 2; ++j) {
      const int nb = n0 + j * 16 + quad * 4;
      ushort4 o;
      o.x = f2bf(acc[i][j][0]); o.y = f2bf(acc[i][j][1]);
      o.z = f2bf(acc[i][j][2]); o.w = f2bf(acc[i][j][3]);
      *(ushort4*)(Cout + (size_t)token * ldc + nb) = o;
    }
  }
}

// ---------------- fused mamba prep + chunk-local scan (LDS-prefetched conv) ------------
__global__ __launch_bounds__(256)
void mprep_kernel(const ushort* __restrict__ xz1, const float* __restrict__ cwT,
                  const float* __restrict__ cb, const ushort* __restrict__ Wxt,
                  const ushort* __restrict__ Wdtt, const float* __restrict__ bdt,
                  const float* __restrict__ Alog,
                  ushort* __restrict__ xmb, ushort* __restrict__ dlt,
                  float* __restrict__ bc, unsigned* __restrict__ PE)
{
  __shared__ ushort sxm[32][204];
  __shared__ union {
    ushort sxz[34][200];    // phase a: staged xz1 rows [T0-2, T0+32), cols 0..191
    ushort sdlt[32][204];   // phase b/c: delta
  } u;
  __shared__ float sbc[32][36];
  const int tid = threadIdx.x;
  const int bid = blockIdx.x;
  const int T0 = bid * 32;
  const f32x4 z4 = {0.f, 0.f, 0.f, 0.f};

  // phase a0: bulk coalesced prefetch of xz1 tile -> LDS
  for (int i = tid; i < 34 * 24; i += 256) {
    int r = i / 24, c = i % 24;
    int t = T0 - 2 + r;
    uint4 v = make_uint4(0u, 0u, 0u, 0u);
    if (t >= 0) v = *(const uint4*)(xz1 + (size_t)t * 384 + c * 8);
    *(uint4*)&u.sxz[r][c * 8] = v;
  }
  __syncthreads();

  // phase a1: causal conv1d + bias + SiLU from LDS
  for (int task = tid; task < 1536; task += 256) {
    int dq = task % 48, tok = task / 48;
    int t = T0 + tok, l = t % LSEQ;
    int d = dq * 4;
    float4 b4 = *(const float4*)(cb + d);
    float a0 = b4.x, a1 = b4.y, a2 = b4.z, a3 = b4.w;
#pragma unroll
    for (int k = 0; k < 3; ++k) {
      if (l + k - 2 < 0) continue;
      const ushort4 v = *(const ushort4*)&u.sxz[tok + k][d];
      const float4 w4 = *(const float4*)(cwT + k * 192 + d);
      a0 = fmaf(bf2f(v.x), w4.x, a0);
      a1 = fmaf(bf2f(v.y), w4.y, a1);
      a2 = fmaf(bf2f(v.z), w4.z, a2);
      a3 = fmaf(bf2f(v.w), w4.w, a3);
    }
    ushort4 o;
    o.x = f2bf(silu_f(a0)); o.y = f2bf(silu_f(a1));
    o.z = f2bf(silu_f(a2)); o.w = f2bf(silu_f(a3));
    *(ushort4*)&sxm[tok][d] = o;
    *(ushort4*)(xmb + (size_t)t * DI + d) = o;
  }
  __syncthreads();

  // phase b: x_proj (B,C | dt->dt_proj) by wave role
  {
    const int wv = tid >> 6, lane = tid & 63;
    const int l16 = lane & 15, quad = lane >> 4;
    const int s = wv & 1, role = wv >> 1;
    const int tokb = s * 16;
    if (role == 0) {
      f32x4 aB = z4, aC = z4;
#pragma unroll
      for (int k0 = 0; k0 < 192; k0 += 32) {
        bf16x8 uf = *(const bf16x8*)&sxm[tokb + l16][k0 + quad * 8];
        bf16x8 wB = *(const bf16x8*)(Wxt + (size_t)(l16) * 192 + k0 + quad * 8);
        bf16x8 wC = *(const bf16x8*)(Wxt + (size_t)(16 + l16) * 192 + k0 + quad * 8);
        aB = __builtin_amdgcn_mfma_f32_16x16x32_bf16(wB, uf, aB, 0, 0, 0);
        aC = __builtin_amdgcn_mfma_f32_16x16x32_bf16(wC, uf, aC, 0, 0, 0);
      }
      float4 vB = make_float4(aB[0], aB[1], aB[2], aB[3]);
      float4 vC = make_float4(aC[0], aC[1], aC[2], aC[3]);
      *(float4*)&sbc[tokb + l16][quad * 4] = vB;
      *(float4*)&sbc[tokb + l16][16 + quad * 4] = vC;
      *(float4*)(bc + (size_t)(T0 + tokb + l16) * 32 + quad * 4) = vB;
      *(float4*)(bc + (size_t)(T0 + tokb + l16) * 32 + 16 + quad * 4) = vC;
    } else {
      f32x4 aD = z4;
#pragma unroll
      for (int k0 = 0; k0 < 192; k0 += 32) {
        bf16x8 uf = *(const bf16x8*)&sxm[tokb + l16][k0 + quad * 8];
        bf16x8 wD = *(const bf16x8*)(Wxt + (size_t)(32 + l16) * 192 + k0 + quad * 8);
        aD = __builtin_amdgcn_mfma_f32_16x16x32_bf16(wD, uf, aD, 0, 0, 0);
      }
      bf16x8 dtf;
#pragma unroll
      for (int j = 0; j < 8; ++j) {
        int n = quad * 8 + j;
        int src = ((n >> 2) & 3) * 16 + l16;
        float tv = __shfl(aD[j & 3], src);
        dtf[j] = (short)((n < 16) ? f2bf(tv) : (ushort)0);
      }
      f32x4 a2[12];
#pragma unroll
      for (int jj = 0; jj < 12; ++jj) {
        bf16x8 wf = *(const bf16x8*)(Wdtt + (size_t)(jj * 16 + l16) * 32 + quad * 8);
        a2[jj] = __builtin_amdgcn_mfma_f32_16x16x32_bf16(wf, dtf, z4, 0, 0, 0);
      }
#pragma unroll
      for (int jj = 0; jj < 12; ++jj) {
        const int nb = jj * 16 + quad * 4;
        const float4 b4 = *(const float4*)(bdt + nb);
        ushort4 o;
        o.x = f2bf(softplus_f(a2[jj][0] + b4.x));
        o.y = f2bf(softplus_f(a2[jj][1] + b4.y));
        o.z = f2bf(softplus_f(a2[jj][2] + b4.z));
        o.w = f2bf(softplus_f(a2[jj][3] + b4.w));
        *(ushort4*)&u.sdlt[tokb + l16][nb] = o;
        *(ushort4*)(dlt + (size_t)(T0 + tokb + l16) * DI + nb) = o;
      }
    }
  }
  __syncthreads();

  // phase c: chunk-local scan -> packed P|E
  for (int task = tid; task < 384; task += 256) {
    const int d = task % 192, c = task / 192;
    float Av[16];
#pragma unroll
    for (int j = 0; j < 16; ++j) Av[j] = -__expf(Alog[d * 16 + j]);
    float e[16];
#pragma unroll
    for (int j = 0; j < 16; ++j) e[j] = 0.f;
    float sdl = 0.f;
    for (int l = 0; l < CHUNK; ++l) {
      const int tl = c * 16 + l;
      float dl = bf2f(u.sdlt[tl][d]);
      float uu = bf2f(sxm[tl][d]);
      const float4 B0 = *(const float4*)&sbc[tl][0];
      const float4 B1 = *(const float4*)&sbc[tl][4];
      const float4 B2 = *(const float4*)&sbc[tl][8];
      const float4 B3 = *(const float4*)&sbc[tl][12];
      const float Bv[16] = {B0.x, B0.y, B0.z, B0.w, B1.x, B1.y, B1.z, B1.w,
                            B2.x, B2.y, B2.z, B2.w, B3.x, B3.y, B3.z, B3.w};
      float du = dl * uu;
      sdl += dl;
#pragma unroll
      for (int j = 0; j < 16; ++j) {
        float a = __expf(dl * Av[j]);
        e[j] = fmaf(a, e[j], du * Bv[j]);
      }
    }
    const int batch = bid / 288;
    const int gci = (bid % 288) * 2 + c;
    size_t base = ((size_t)(batch * NCHUNK + gci)) * QDN + d;
#pragma unroll
    for (int j = 0; j < 16; ++j) {
      unsigned p = f2bf(__expf(Av[j] * sdl));
      unsigned ev = f2bf(e[j]);
      PE[base + j * 192] = (p << 16) | ev;
    }
  }
}

// ---------------- scan2a: per-super product/accum (packed P|E in) ----------------
__global__ __launch_bounds__(256)
void scan2a_kernel(const unsigned* __restrict__ PE,
                   float* __restrict__ SP, float* __restrict__ SE)
{
  int id = blockIdx.x * 256 + threadIdx.x;  // BATCH*NSUP*QDN = 147456
  int q = id % QDN;
  int s = (id / QDN) % NSUP;
  int b = id / (QDN * NSUP);
  float cp = 1.f, ce = 0.f;
#pragma unroll 6
  for (int c = 0; c < SUP; ++c) {
    unsigned pe = PE[((size_t)(b * NCHUNK + s * SUP + c)) * QDN + q];
    float p = bf2f((ushort)(pe >> 16));
    float e = bf2f((ushort)(pe & 0xFFFF));
    ce = fmaf(p, ce, e);
    cp *= p;
  }
  SP[id] = cp; SE[id] = ce;
}

// ---------------- scan2b: serial over NSUP supers ----------------
__global__ __launch_bounds__(256)
void scan2b_kernel(const float* __restrict__ SP, const float* __restrict__ SE,
                   float* __restrict__ Hsup)
{
  int id = blockIdx.x * 256 + threadIdx.x;  // BATCH*QDN = 6144
  int q = id % QDN;
  int b = id / QDN;
  float carry = 0.f;
#pragma unroll
  for (int s = 0; s < NSUP; ++s) {
    size_t idx = ((size_t)(b * NSUP + s)) * QDN + q;
    Hsup[idx] = carry;
    carry = fmaf(SP[idx], carry, SE[idx]);
  }
}

// ---------------- scan2c: expand to per-chunk inbound (bf16 out) ----------------
__global__ __launch_bounds__(256)
void scan2c_kernel(const unsigned* __restrict__ PE, const float* __restrict__ Hsup,
                   ushort* __restrict__ Hin)
{
  int id = blockIdx.x * 256 + threadIdx.x;  // 147456
  int q = id % QDN;
  int s = (id / QDN) % NSUP;
  int b = id / (QDN * NSUP);
  float h = Hsup[id];
#pragma unroll 6
  for (int c = 0; c < SUP; ++c) {
    size_t idx = ((size_t)(b * NCHUNK + s * SUP + c)) * QDN + q;
    Hin[idx] = f2bf(h);
    unsigned pe = PE[idx];
    float p = bf2f((ushort)(pe >> 16));
    float e = bf2f((ushort)(pe & 0xFFFF));
    h = fmaf(p, h, e);
  }
}

// ---------------- fused scan3 replay + m_out_proj (gate) + out_proj (+residual) --------
// LDS-prefetched inputs (dlt/xmb/z) to break the scan loop's dependent global loads.
__global__ __launch_bounds__(256)
void scan3_outproj_kernel(const ushort* __restrict__ dlt, const ushort* __restrict__ xmb,
                          const float* __restrict__ bc, const float* __restrict__ Alog,
                          const float* __restrict__ Dv, const ushort* __restrict__ xz1,
                          const ushort* __restrict__ Hin, const ushort* __restrict__ xz0,
                          const ushort* __restrict__ Wt2, const ushort* __restrict__ Wt3,
                          const float* __restrict__ x, float* __restrict__ out)
{
  __shared__ float sBC[CHUNK][32];
  __shared__ ushort sY[16][204];
  __shared__ union {
    struct { ushort d[16][204]; ushort u[16][204]; ushort z[16][204]; } in;
    ushort yg[16][204];
  } su;
  const int tid = threadIdx.x;
  const int g = blockIdx.x % NCHUNK;
  const int b = blockIdx.x / NCHUNK;
  const int t0 = b * LSEQ + g * CHUNK;
  const f32x4 z4 = {0.f, 0.f, 0.f, 0.f};

  // prefetch: B|C + dlt + xmb + z, all coalesced independent loads
  for (int i = tid; i < CHUNK * 32; i += 256) {
    int l = i >> 5, j = i & 31;
    sBC[l][j] = bc[(size_t)(t0 + l) * 32 + j];
  }
  for (int i = tid; i < 16 * 24 * 3; i += 256) {
    int which = i / 384;
    int r = (i % 384) / 24, c = (i % 384) % 24;
    int t = t0 + r;
    uint4 v;
    ushort* dst;
    if (which == 0)      { v = *(const uint4*)(dlt + (size_t)t * DI + c * 8);        dst = &su.in.d[r][c * 8]; }
    else if (which == 1) { v = *(const uint4*)(xmb + (size_t)t * DI + c * 8);        dst = &su.in.u[r][c * 8]; }
    else                 { v = *(const uint4*)(xz1 + (size_t)t * 384 + 192 + c * 8); dst = &su.in.z[r][c * 8]; }
    *(uint4*)dst = v;
  }
  __syncthreads();

  // scan replay on threads 0..191 (one d each), all inputs in LDS
  if (tid < 192) {
    const int d = tid;
    float Av[16];
#pragma unroll
    for (int j = 0; j < 16; ++j) Av[j] = -__expf(Alog[d * 16 + j]);
    const float Dd = Dv[d];
    float h[16];
    {
      size_t hb = ((size_t)(b * NCHUNK + g)) * QDN + d;
#pragma unroll
      for (int j = 0; j < 16; ++j) h[j] = bf2f(Hin[hb + j * 192]);
    }
#pragma unroll 4
    for (int l = 0; l < CHUNK; ++l) {
      float dl = bf2f(su.in.d[l][d]);
      float u  = bf2f(su.in.u[l][d]);
      float z  = bf2f(su.in.z[l][d]);
      float du = dl * u;
      float y0 = 0.f, y1 = 0.f, y2 = 0.f, y3 = 0.f;
#pragma unroll
      for (int j = 0; j < 16; ++j) {
        float a = __expf(dl * Av[j]);
        h[j] = fmaf(a, h[j], du * sBC[l][j]);
        float hc = h[j] * sBC[l][16 + j];
        if ((j & 3) == 0) y0 += hc;
        else if ((j & 3) == 1) y1 += hc;
        else if ((j & 3) == 2) y2 += hc;
        else y3 += hc;
      }
      float y = (y0 + y1) + (y2 + y3) + u * Dd;
      sY[l][d] = f2bf(y * silu_f(z));
    }
  }
  __syncthreads();   // closes scan reads of su.in before GEMM1 writes su.yg

  const int wv = tid >> 6, lane = tid & 63;
  const int l16 = lane & 15, quad = lane >> 4;
  const int token = t0 + l16;

  // GEMM1: yg[16][192] = y @ Wt2^T + silu gate
  {
    f32x4 acc1[3] = {z4, z4, z4};
#pragma unroll
    for (int k0 = 0; k0 < 192; k0 += 32) {
      bf16x8 af = *(const bf16x8*)&sY[l16][k0 + quad * 8];
#pragma unroll
      for (int i = 0; i < 3; ++i) {
        const int tt = wv + i * 4;
        bf16x8 wf = *(const bf16x8*)(Wt2 + (size_t)(tt * 16 + l16) * 192 + k0 + quad * 8);
        acc1[i] = __builtin_amdgcn_mfma_f32_16x16x32_bf16(wf, af, acc1[i], 0, 0, 0);
      }
    }
#pragma unroll
    for (int i = 0; i < 3; ++i) {
      const int nb = (wv + i * 4) * 16 + quad * 4;
      const ushort4 g4 = *(const ushort4*)(xz0 + (size_t)token * 384 + 192 + nb);
      unsigned p0 = (unsigned)f2bf(acc1[i][0] * silu_f(bf2f(g4.x)))
                  | ((unsigned)f2bf(acc1[i][1] * silu_f(bf2f(g4.y))) << 16);
      unsigned p1 = (unsigned)f2bf(acc1[i][2] * silu_f(bf2f(g4.z)))
                  | ((unsigned)f2bf(acc1[i][3] * silu_f(bf2f(g4.w))) << 16);
      unsigned* dst = (unsigned*)&su.yg[l16][nb];
      dst[0] = p0; dst[1] = p1;
    }
  }
  __syncthreads();

  // GEMM2: out[16][96] = yg @ Wt3^T + x
#pragma unroll
  for (int rep = 0; rep < 2; ++rep) {
    const int tt = wv + rep * 4;
    if (tt >= 6) break;
    f32x4 acc2 = z4;
#pragma unroll
    for (int k0 = 0; k0 < 192; k0 += 32) {
      bf16x8 af = *(const bf16x8*)&su.yg[l16][k0 + quad * 8];
      bf16x8 wf = *(const bf16x8*)(Wt3 + (size_t)(tt * 16 + l16) * 192 + k0 + quad * 8);
      acc2 = __builtin_amdgcn_mfma_f32_16x16x32_bf16(wf, af, acc2, 0, 0, 0);
    }
    const int nb = tt * 16 + quad * 4;
    const float4 r4 = *(const float4*)(x + (size_t)token * 96 + nb);
    *(float4*)(out + (size_t)token * 96 + nb) =
        make_float4(acc2[0] + r4.x, acc2[1] + r4.y, acc2[2] + r4.z, acc2[3] + r4.w);
  }
}

// ---------------- launch ----------------
extern "C" void kernel_launch(void* const* d_in, const int* in_sizes, int n_in,
                              void* d_out, int out_size, void* d_ws, size_t ws_size,
                              hipStream_t stream)
{
  const float* x         = (const float*)d_in[0];
  const float* norm_w    = (const float*)d_in[1];
  const float* norm_b    = (const float*)d_in[2];
  const float* in_proj_w = (const float*)d_in[3];
  const float* conv2d_w  = (const float*)d_in[4];
  const float* m_in_proj = (const float*)d_in[5];
  const float* m_c1d_w   = (const float*)d_in[6];
  const float* m_c1d_b   = (const float*)d_in[7];
  const float* m_x_proj  = (const float*)d_in[8];
  const float* m_dt_w    = (const float*)d_in[9];
  const float* m_dt_b    = (const float*)d_in[10];
  const float* m_A_log   = (const float*)d_in[11];
  const float* m_D       = (const float*)d_in[12];
  const float* m_out_w   = (const float*)d_in[13];
  const float* out_w     = (const float*)d_in[14];
  float* out = (float*)d_out;

  char* wp = (char*)d_ws;
  auto alloc = [&](size_t bytes) {
    char* r = wp; wp += (bytes + 255) & ~(size_t)255; return r;
  };
  ushort* Wt0    = (ushort*)alloc(36864 * 2);      // [384][96]
  ushort* Wt1    = (ushort*)alloc(73728 * 2);      // [384][192]
  ushort* Wt2    = (ushort*)alloc(36864 * 2);      // [192][192]
  ushort* Wt3    = (ushort*)alloc(24576 * 2);      // [128][192]
  ushort* Wxt    = (ushort*)alloc(9216 * 2);       // [48][192]
  ushort* Wdtt   = (ushort*)alloc(6144 * 2);       // [192][32]
  float*  cw1T   = (float*)alloc(576 * 4);         // [3][192]
  ushort* xz0    = (ushort*)alloc((size_t)TT * 384 * 2);
  ushort* xc_bf  = (ushort*)alloc((size_t)TT * 192 * 2);
  ushort* xz1    = (ushort*)alloc((size_t)TT * 384 * 2);
  ushort* xmb_bf = (ushort*)alloc((size_t)TT * 192 * 2);
  float*  bc     = (float*)alloc((size_t)TT * 32 * 4);
  ushort* dlt    = (ushort*)alloc((size_t)TT * 192 * 2);
  unsigned* PE   = (unsigned*)alloc((size_t)BATCH * NCHUNK * QDN * 4);
  float*  SP     = (float*)alloc((size_t)BATCH * NSUP * QDN * 4);
  float*  SE     = (float*)alloc((size_t)BATCH * NSUP * QDN * 4);
  float*  Hsup   = (float*)alloc((size_t)BATCH * NSUP * QDN * 4);
  ushort* Hin    = (ushort*)alloc((size_t)BATCH * NCHUNK * QDN * 2);

  castw_kernel<<<735, 256, 0, stream>>>(in_proj_w, m_in_proj, m_out_w, out_w,
                                        m_x_proj, m_dt_w, m_c1d_w,
                                        Wt0, Wt1, Wt2, Wt3, Wxt, Wdtt, cw1T);
  ln_inproj_kernel<<<dim3(TT / 128, 6), 256, 0, stream>>>(x, norm_w, norm_b, Wt0, xz0);
  conv2d_silu_kernel<<<TT * 48 / 256, 256, 0, stream>>>(xz0, conv2d_w, xc_bf);
  mfma_gemm_kernel<<<dim3(TT / 128, 6), 256, 0, stream>>>(xc_bf, 192, Wt1, 192, xz1, 384, 192);
  mprep_kernel<<<TT / 32, 256, 0, stream>>>(xz1, cw1T, m_c1d_b, Wxt, Wdtt, m_dt_b,
                                            m_A_log, xmb_bf, dlt, bc, PE);
  scan2a_kernel<<<BATCH * NSUP * QDN / 256, 256, 0, stream>>>(PE, SP, SE);
  scan2b_kernel<<<BATCH * QDN / 256, 256, 0, stream>>>(SP, SE, Hsup);
  scan2c_kernel<<<BATCH * NSUP * QDN / 256, 256, 0, stream>>>(PE, Hsup, Hin);
  scan3_outproj_kernel<<<BATCH * NCHUNK, 256, 0, stream>>>(
      dlt, xmb_bf, bc, m_A_log, m_D, xz1, Hin, xz0, Wt2, Wt3, x, out);
}